// Round 8
// baseline (76.991 us; speedup 1.0000x reference)
//
#include <hip/hip_runtime.h>

#define N_CLS 8192
#define DIM   2048
#define DIMT  4096          // XT row bytes: 8192 fp4 elems / 2
#define BKB   128           // K-tile bytes per row = 256 fp4 elems
#define NKT   32            // 4096 / 128 K-tiles

typedef __attribute__((ext_vector_type(16))) float f32x16;
typedef __attribute__((ext_vector_type(8)))  int   i32x8;

__device__ __forceinline__ void load16(const char* g, char* l) {
    __builtin_amdgcn_global_load_lds(
        (const __attribute__((address_space(1))) void*)g,
        (__attribute__((address_space(3))) void*)l, 16, 0, 0);
}
__device__ __forceinline__ void vm0() {
    asm volatile("s_waitcnt vmcnt(0)" ::: "memory");
}
__device__ __forceinline__ void hard_barrier() {
    __builtin_amdgcn_sched_barrier(0);
    __builtin_amdgcn_s_barrier();
    __builtin_amdgcn_sched_barrier(0);
}

__device__ __forceinline__ unsigned f2bf(float f) {
    union { float f; unsigned u; } a; a.f = f;
    return (a.u + 0x7fffu + ((a.u >> 16) & 1u)) >> 16;
}
__device__ __forceinline__ float bf2f(unsigned short u) {
    union { unsigned u; float f; } a; a.u = ((unsigned)u) << 16;
    return a.f;
}
// ---- e2m1 encode: nearest of {0,.5,1,1.5,2,3,4,6} with sign ----
__device__ __forceinline__ unsigned enc1(float v, float sc) {
    float a = fabsf(v) * sc;
    unsigned c = (a >= 0.25f) + (a >= 0.75f) + (a >= 1.25f) + (a >= 1.75f) +
                 (a >= 2.5f)  + (a >= 3.5f)  + (a >= 5.0f);
    return c | ((__float_as_uint(v) >> 28) & 8u);
}

// ---------------- kernel 1: per-row 1/||row|| ----------------
__global__ __launch_bounds__(256) void row_norms(const float* __restrict__ x,
                                                 float* __restrict__ inv) {
    const int wid = threadIdx.x >> 6, lane = threadIdx.x & 63;
    const int row = blockIdx.x * 4 + wid;
    const float4* xr = reinterpret_cast<const float4*>(x + (size_t)row * DIM);
    float s = 0.0f;
#pragma unroll
    for (int k = 0; k < 8; ++k) {
        float4 v = xr[lane + 64 * k];
        s += v.x*v.x + v.y*v.y + v.z*v.z + v.w*v.w;
    }
#pragma unroll
    for (int off = 32; off > 0; off >>= 1) s += __shfl_down(s, off);
    if (lane == 0) inv[row] = 1.0f / fmaxf(sqrtf(s), 1e-12f);
}

// ---- kernel 2: 128x128 tile transpose + fp4 quantize (x64) + S partials ----
// grid (64 i-chunks, 16 d-chunks), 256 threads
__global__ __launch_bounds__(256) void transpose_quant(const float* __restrict__ x,
                                                       const float* __restrict__ inv,
                                                       unsigned char* __restrict__ xt,
                                                       float* __restrict__ Spart) {
    __shared__ unsigned short tile[128][130];
    __shared__ float invs[128];
    const int ic = blockIdx.x, dc = blockIdx.y;
    const int t = threadIdx.x;
    if (t < 128) invs[t] = inv[ic * 128 + t];
    __syncthreads();
    // load 128 rows x 128 d of x, normalize, bf16 into LDS
#pragma unroll
    for (int it = 0; it < 16; ++it) {
        const int seg = it * 256 + t;
        const int r = seg >> 5;            // 0..127
        const int c4 = (seg & 31) * 4;     // 0..124
        float4 v = *reinterpret_cast<const float4*>(
            x + (size_t)(ic * 128 + r) * DIM + dc * 128 + c4);
        const float iv = invs[r];
        tile[r][c4 + 0] = (unsigned short)f2bf(v.x * iv);
        tile[r][c4 + 1] = (unsigned short)f2bf(v.y * iv);
        tile[r][c4 + 2] = (unsigned short)f2bf(v.z * iv);
        tile[r][c4 + 3] = (unsigned short)f2bf(v.w * iv);
    }
    __syncthreads();
    // deterministic S partial: Spart[ic][d]
    if (t < 128) {
        float s = 0.0f;
        for (int i = 0; i < 128; ++i) s += bf2f(tile[i][t]);
        Spart[(size_t)ic * DIM + dc * 128 + t] = s;
    }
    // transposed fp4 write: thread owns (d, half): 64 i's -> 32 bytes
    const int d = t & 127, half = t >> 7;
    unsigned w[8];
#pragma unroll
    for (int j = 0; j < 8; ++j) {
        unsigned wd = 0;
#pragma unroll
        for (int b = 0; b < 4; ++b) {
            const int i0 = half * 64 + (j * 4 + b) * 2;
            unsigned byte = enc1(bf2f(tile[i0][d]), 64.0f) |
                            (enc1(bf2f(tile[i0 + 1][d]), 64.0f) << 4);
            wd |= byte << (8 * b);
        }
        w[j] = wd;
    }
    const size_t off = (size_t)(dc * 128 + d) * DIMT + ic * 64 + half * 32;
    int4 o0 = make_int4((int)w[0], (int)w[1], (int)w[2], (int)w[3]);
    int4 o1 = make_int4((int)w[4], (int)w[5], (int)w[6], (int)w[7]);
    *reinterpret_cast<int4*>(xt + off) = o0;
    *reinterpret_cast<int4*>(xt + off + 16) = o1;
}

// read one 16-byte (K=64, fp4) fragment from a swizzled LDS row
__device__ __forceinline__ int4 rd16(const char* rowp, int cc, int swz) {
    return *reinterpret_cast<const int4*>(rowp + (((cc) ^ swz) << 4));
}
__device__ __forceinline__ i32x8 op4(int4 d) {
    i32x8 r;
    r[0] = d.x; r[1] = d.y; r[2] = d.z; r[3] = d.w;
    r[4] = d.x; r[5] = d.y; r[6] = d.z; r[7] = d.w;
    return r;
}
#define MFMA4(A, B, C) __builtin_amdgcn_mfma_scale_f32_32x32x64_f8f6f4( \
    (A), (B), (C), 4, 4, 0, 0x7F7F7F7F, 0, 0x7F7F7F7F)

// ---- kernel 3: M = XT·XT^T (= Xn^T Xn) 128x128 fp4 tiles, fused ||M||_F^2 ----
// grid 256 = full 16x16 tile grid, 4 waves, per-wave 64x64 (2x2 MFMA units)
__global__ __launch_bounds__(256) void msyrk(const char* __restrict__ xt,
                                             float* __restrict__ qpart) {
    constexpr int A_SLOT = 128 * BKB;          // 16 KiB
    __shared__ __align__(16) char As[2 * A_SLOT];
    __shared__ __align__(16) char Bs[2 * A_SLOT];
    __shared__ float red[4];

    const int ba = blockIdx.x >> 4, bb = blockIdx.x & 15;
    const int tid = threadIdx.x;
    const int lane = tid & 63, wid = tid >> 6;
    const int wr = wid >> 1, wcb = wid & 1;    // wave grid 2 x 2

    const int srow = lane >> 3;                      // 0..7 within an 8-row call
    const int gch  = ((lane & 7) ^ srow) << 4;       // involutive 16B-chunk XOR
    const char* gA = xt + (size_t)(ba * 128 + wid * 32 + srow) * DIMT + gch;
    const char* gB = xt + (size_t)(bb * 128 + wid * 32 + srow) * DIMT + gch;

    auto stageA = [&](int tt, int s) {
#pragma unroll
        for (int q = 0; q < 4; ++q)
            load16(gA + (size_t)(q * 8) * DIMT + tt * BKB,
                   &As[s * A_SLOT + wid * 4096 + q * 1024]);
    };
    auto stageB = [&](int tt, int s) {
#pragma unroll
        for (int q = 0; q < 4; ++q)
            load16(gB + (size_t)(q * 8) * DIMT + tt * BKB,
                   &Bs[s * A_SLOT + wid * 4096 + q * 1024]);
    };

    const int lr = lane & 31, hi = lane >> 5, swz = lane & 7;

    f32x16 acc[2][2];
#pragma unroll
    for (int m = 0; m < 2; ++m)
#pragma unroll
        for (int n = 0; n < 2; ++n)
#pragma unroll
            for (int r = 0; r < 16; ++r) acc[m][n][r] = 0.0f;

    stageA(0, 0); stageB(0, 0);
    vm0();
    hard_barrier();

#define READ_S(AV, BV, S)                                                    \
    do {                                                                     \
        _Pragma("unroll")                                                    \
        for (int m = 0; m < 2; ++m)                                          \
            AV[m] = rd16(arow + m * 32 * BKB, 2 * (S) + hi, swz);            \
        _Pragma("unroll")                                                    \
        for (int n = 0; n < 2; ++n)                                          \
            BV[n] = rd16(brow + n * 32 * BKB, 2 * (S) + hi, swz);            \
    } while (0)
#define MFMA_S(AV, BV)                                                       \
    do {                                                                     \
        _Pragma("unroll")                                                    \
        for (int m = 0; m < 2; ++m)                                          \
            _Pragma("unroll")                                                \
            for (int n = 0; n < 2; ++n)                                      \
                acc[m][n] = MFMA4(op4(AV[m]), op4(BV[n]), acc[m][n]);        \
    } while (0)

    for (int t = 0; t < NKT; ++t) {
        const char* arow = &As[(t & 1) * A_SLOT] + (wr * 64 + lr) * BKB;
        const char* brow = &Bs[(t & 1) * A_SLOT] + (wcb * 64 + lr) * BKB;
        const int ns = (t & 1) ^ 1;
        if (t + 1 < NKT) { stageA(t + 1, ns); stageB(t + 1, ns); }

        int4 aC[2], bC[2], aN[2], bN[2];
        READ_S(aC, bC, 0);
        READ_S(aN, bN, 1);
        MFMA_S(aC, bC);
        READ_S(aC, bC, 2);
        MFMA_S(aN, bN);
        READ_S(aN, bN, 3);
        MFMA_S(aC, bC);
        MFMA_S(aN, bN);

        if (t < NKT - 1) {
            vm0();              // t+1 stages issued a whole tile ago
            hard_barrier();
        }
    }
#undef READ_S
#undef MFMA_S

    // epilogue: Q partial = sum (raw/4096)^2 over this block's M-tile
    float s = 0.0f;
#pragma unroll
    for (int m = 0; m < 2; ++m)
#pragma unroll
        for (int n = 0; n < 2; ++n)
#pragma unroll
            for (int r = 0; r < 16; ++r) {
                float v = acc[m][n][r] * (1.0f / 4096.0f);
                s += v * v;
            }
#pragma unroll
    for (int off = 32; off > 0; off >>= 1) s += __shfl_down(s, off);
    if (lane == 0) red[wid] = s;
    __syncthreads();
    if (tid == 0) qpart[blockIdx.x] = red[0] + red[1] + red[2] + red[3];
}

// ---------------- kernel 4: combine S partials ----------------
__global__ __launch_bounds__(256) void scombine(const float* __restrict__ Spart,
                                                float* __restrict__ S) {
    const int d = blockIdx.x * 256 + threadIdx.x;
    float s = 0.0f;
    for (int ic = 0; ic < 64; ++ic) s += Spart[(size_t)ic * DIM + d];
    S[d] = s;
}

// ---------------- kernel 5: finalize ----------------
__global__ __launch_bounds__(256) void finalize(const float* __restrict__ qpart,
                                                const float* __restrict__ S,
                                                float* __restrict__ out) {
    const int t = threadIdx.x;
    float q = qpart[t];
    float s2 = 0.0f;
#pragma unroll
    for (int k = 0; k < 8; ++k) {
        float v = S[t + 256 * k];
        s2 += v * v;
    }
#pragma unroll
    for (int off = 32; off > 0; off >>= 1) {
        q  += __shfl_down(q, off);
        s2 += __shfl_down(s2, off);
    }
    __shared__ float redq[4], reds[4];
    if ((t & 63) == 0) { redq[t >> 6] = q; reds[t >> 6] = s2; }
    __syncthreads();
    if (t == 0) {
        double Q  = (double)redq[0] + redq[1] + redq[2] + redq[3];
        double S2 = (double)reds[0] + reds[1] + reds[2] + reds[3];
        const double N = 8192.0, NN1 = 8192.0 * 8191.0;
        double ans = (N + exp(-2.0) * (NN1 + 2.0 * (S2 - N) + 2.0 * (Q - N))) / NN1;
        out[0] = (float)ans;
    }
}

extern "C" void kernel_launch(void* const* d_in, const int* in_sizes, int n_in,
                              void* d_out, int out_size, void* d_ws, size_t ws_size,
                              hipStream_t stream) {
    const float* x = (const float*)d_in[0];
    float* out = (float*)d_out;
    // ws layout: xt fp4 8MB | inv 32KB | Spart 512KB | S 8KB | qpart 1KB
    unsigned char* xt = (unsigned char*)d_ws;
    float* inv   = (float*)((char*)d_ws + (size_t)2048 * DIMT);
    float* Spart = inv + N_CLS;
    float* S     = Spart + (size_t)64 * DIM;
    float* qpart = S + DIM;

    row_norms<<<N_CLS / 4, 256, 0, stream>>>(x, inv);
    transpose_quant<<<dim3(64, 16), 256, 0, stream>>>(x, inv, xt, Spart);
    msyrk<<<256, 256, 0, stream>>>((const char*)xt, qpart);
    scombine<<<DIM / 256, 256, 0, stream>>>(Spart, S);
    finalize<<<1, 256, 0, stream>>>(qpart, S, out);
}

// Round 9
// 72.972 us; speedup vs baseline: 1.0551x; 1.0551x over previous
//
#include <hip/hip_runtime.h>

#define N_CLS 8192
#define DIMB  1024          // bytes per row (fp4: 0.5 B/elem, 2048 elems)
#define BKB   128           // K-tile bytes per row = 256 elements
#define NBT   64            // 8192/128 tile grid
#define NTILES 2080         // NBT*(NBT+1)/2 upper-tri 128x128 tiles
#define NT    8             // DIMB/BKB K-tiles

typedef __attribute__((ext_vector_type(16))) float f32x16;
typedef __attribute__((ext_vector_type(8)))  int   i32x8;

__device__ __forceinline__ void load16(const char* g, char* l) {
    __builtin_amdgcn_global_load_lds(
        (const __attribute__((address_space(1))) void*)g,
        (__attribute__((address_space(3))) void*)l, 16, 0, 0);
}
template <int N> __device__ __forceinline__ void waitcnt_vm() {
    if constexpr (N == 0)      asm volatile("s_waitcnt vmcnt(0)" ::: "memory");
    else if constexpr (N == 8) asm volatile("s_waitcnt vmcnt(8)" ::: "memory");
}
__device__ __forceinline__ void hard_barrier() {
    __builtin_amdgcn_sched_barrier(0);
    __builtin_amdgcn_s_barrier();
    __builtin_amdgcn_sched_barrier(0);
}

// ---- e2m1 encode: nearest of {0,.5,1,1.5,2,3,4,6} with sign ----
__device__ __forceinline__ unsigned enc1(float v, float sc) {
    float a = fabsf(v) * sc;
    unsigned c = (a >= 0.25f) + (a >= 0.75f) + (a >= 1.25f) + (a >= 1.75f) +
                 (a >= 2.5f)  + (a >= 3.5f)  + (a >= 5.0f);
    return c | ((__float_as_uint(v) >> 28) & 8u);
}
__device__ __forceinline__ unsigned short enc4(float4 v, float sc) {
    return (unsigned short)(enc1(v.x, sc) | (enc1(v.y, sc) << 4) |
                            (enc1(v.z, sc) << 8) | (enc1(v.w, sc) << 12));
}

// ------- kernel 1: wave-per-row L2-normalize, scale x64, quantize to e2m1 -------
__global__ __launch_bounds__(256) void normalize_rows(const float* __restrict__ x,
                                                      unsigned char* __restrict__ xq) {
    const int wid = threadIdx.x >> 6, lane = threadIdx.x & 63;
    const int row = blockIdx.x * 4 + wid;
    const float4* xr = reinterpret_cast<const float4*>(x + (size_t)row * 2048);
    float4 v[8];
    float s = 0.0f;
#pragma unroll
    for (int k = 0; k < 8; ++k) {
        v[k] = xr[lane + 64 * k];
        s += v[k].x*v[k].x + v[k].y*v[k].y + v[k].z*v[k].z + v[k].w*v[k].w;
    }
#pragma unroll
    for (int off = 32; off > 0; off >>= 1) s += __shfl_down(s, off);
    s = __shfl(s, 0);
    const float sc = 64.0f / fmaxf(sqrtf(s), 1e-12f);
    unsigned short* orow = reinterpret_cast<unsigned short*>(xq + (size_t)row * DIMB);
#pragma unroll
    for (int k = 0; k < 8; ++k) orow[lane + 64 * k] = enc4(v[k], sc);
}

// read one 16-byte (K=64, fp4) fragment from a swizzled LDS row; dup into both halves
__device__ __forceinline__ i32x8 rdfrag4(const char* rowp, int cc, int swz) {
    int4 d = *reinterpret_cast<const int4*>(rowp + (((cc) ^ swz) << 4));
    i32x8 r;
    r[0] = d.x; r[1] = d.y; r[2] = d.z; r[3] = d.w;
    r[4] = d.x; r[5] = d.y; r[6] = d.z; r[7] = d.w;
    return r;
}

#define MFMA4(A, B, C) __builtin_amdgcn_mfma_scale_f32_32x32x64_f8f6f4( \
    (A), (B), (C), 4, 4, 0, 0x7F7F7F7F, 0, 0x7F7F7F7F)

// ---- kernel 2: 128x128 MX-fp4 gram tile (round-4 schedule), 2 blocks/CU ----
__global__ __launch_bounds__(256, 2) void gram_tile(const char* __restrict__ xq,
                                                    float* __restrict__ partials) {
    constexpr int SLOT = 128 * BKB;            // 16 KiB per matrix per buffer

    __shared__ __align__(16) char As[2 * SLOT];   // 32 KiB
    __shared__ __align__(16) char Bs[2 * SLOT];   // 32 KiB
    __shared__ float red[4];

    int bi = 0, rem = blockIdx.x;               // triangle decode, bi <= bj
    while (rem >= NBT - bi) { rem -= NBT - bi; ++bi; }
    const int bj = bi + rem;

    const int tid = threadIdx.x;
    const int lane = tid & 63, wid = tid >> 6;
    const int wr = wid >> 1, wc = wid & 1;      // wave grid 2 x 2, each 64x64

    // staging (pre-swizzled global source; linear LDS dest) — proven r4 pattern
    const int srow = lane >> 3;                       // 0..7 within an 8-row call
    const int gch  = ((lane & 7) ^ srow) << 4;        // involutive 16B-chunk XOR
    const char* gA = xq + (size_t)(bi * 128 + wid * 32 + srow) * DIMB + gch;
    const char* gB = xq + (size_t)(bj * 128 + wid * 32 + srow) * DIMB + gch;

    auto stageA = [&](int tt, int s) {
#pragma unroll
        for (int q = 0; q < 4; ++q)
            load16(gA + (size_t)(q * 8) * DIMB + tt * BKB,
                   &As[s * SLOT + wid * 4096 + q * 1024]);
    };
    auto stageB = [&](int tt, int s) {
#pragma unroll
        for (int q = 0; q < 4; ++q)
            load16(gB + (size_t)(q * 8) * DIMB + tt * BKB,
                   &Bs[s * SLOT + wid * 4096 + q * 1024]);
    };

    const int lr = lane & 31, hi = lane >> 5, swz = lane & 7;

    f32x16 acc[2][2];
#pragma unroll
    for (int m = 0; m < 2; ++m)
#pragma unroll
        for (int n = 0; n < 2; ++n)
#pragma unroll
            for (int r = 0; r < 16; ++r) acc[m][n][r] = 0.0f;

    stageA(0, 0); stageB(0, 0);
    stageA(1, 1); stageB(1, 1);
    waitcnt_vm<8>();
    hard_barrier();

    for (int t = 0; t < NT; ++t) {
        const char* arow = &As[(t & 1) * SLOT] + (wr * 64 + lr) * BKB;
        const char* brow = &Bs[(t & 1) * SLOT] + (wc * 64 + lr) * BKB;

        // K-slices 0,1 (elements 0..127 of the 256-elem tile)
        i32x8 a0[2], a1[2], b0[2], b1[2];
#pragma unroll
        for (int m = 0; m < 2; ++m) {
            a0[m] = rdfrag4(arow + m * 32 * BKB, 0 + hi, swz);
            a1[m] = rdfrag4(arow + m * 32 * BKB, 2 + hi, swz);
        }
#pragma unroll
        for (int n = 0; n < 2; ++n) {
            b0[n] = rdfrag4(brow + n * 32 * BKB, 0 + hi, swz);
            b1[n] = rdfrag4(brow + n * 32 * BKB, 2 + hi, swz);
        }
        __builtin_amdgcn_s_setprio(1);
#pragma unroll
        for (int m = 0; m < 2; ++m)
#pragma unroll
            for (int n = 0; n < 2; ++n)
                acc[m][n] = MFMA4(a0[m], b0[n], acc[m][n]);
#pragma unroll
        for (int m = 0; m < 2; ++m)
#pragma unroll
            for (int n = 0; n < 2; ++n)
                acc[m][n] = MFMA4(a1[m], b1[n], acc[m][n]);
        __builtin_amdgcn_s_setprio(0);

        // K-slices 2,3 — read before the slot is released
        i32x8 a2[2], a3[2], b2[2], b3[2];
#pragma unroll
        for (int m = 0; m < 2; ++m) {
            a2[m] = rdfrag4(arow + m * 32 * BKB, 4 + hi, swz);
            a3[m] = rdfrag4(arow + m * 32 * BKB, 6 + hi, swz);
        }
#pragma unroll
        for (int n = 0; n < 2; ++n) {
            b2[n] = rdfrag4(brow + n * 32 * BKB, 4 + hi, swz);
            b3[n] = rdfrag4(brow + n * 32 * BKB, 6 + hi, swz);
        }
        asm volatile("s_waitcnt lgkmcnt(0)" ::: "memory");
        hard_barrier();

        const bool st = (t + 2 < NT);
        if (st) stageA(t + 2, t & 1);
        __builtin_amdgcn_s_setprio(1);
#pragma unroll
        for (int m = 0; m < 2; ++m)
#pragma unroll
            for (int n = 0; n < 2; ++n)
                acc[m][n] = MFMA4(a2[m], b2[n], acc[m][n]);
        __builtin_amdgcn_s_setprio(0);
        if (st) stageB(t + 2, t & 1);
        __builtin_amdgcn_s_setprio(1);
#pragma unroll
        for (int m = 0; m < 2; ++m)
#pragma unroll
            for (int n = 0; n < 2; ++n)
                acc[m][n] = MFMA4(a3[m], b3[n], acc[m][n]);
        __builtin_amdgcn_s_setprio(0);

        if (t < NT - 1) {
            if (st) waitcnt_vm<8>(); else waitcnt_vm<0>();
            hard_barrier();
        }
    }

    // epilogue: raw dot = 4096*g (scale 64^2); exp(-max(2-2g,0)) = exp(min(raw/2048-2,0))
    float s = 0.0f;
#pragma unroll
    for (int m = 0; m < 2; ++m)
#pragma unroll
        for (int n = 0; n < 2; ++n)
#pragma unroll
            for (int r = 0; r < 16; ++r)
                s += __expf(fminf(acc[m][n][r] * (1.0f / 2048.0f) - 2.0f, 0.0f));
#pragma unroll
    for (int off = 32; off > 0; off >>= 1) s += __shfl_down(s, off);
    if (lane == 0) red[wid] = s;
    __syncthreads();
    if (tid == 0) {
        float tot = red[0] + red[1] + red[2] + red[3];
        partials[blockIdx.x] = (bi == bj ? 1.0f : 2.0f) * tot;
    }
}

// ---------------- kernel 3: reduce partials, scale ----------------
__global__ __launch_bounds__(256) void finalize(const float* __restrict__ partials,
                                                float* __restrict__ out) {
    float s = 0.f;
    for (int i = threadIdx.x; i < NTILES; i += 256) s += partials[i];
#pragma unroll
    for (int off = 32; off > 0; off >>= 1) s += __shfl_down(s, off);
    __shared__ float red[4];
    if ((threadIdx.x & 63) == 0) red[threadIdx.x >> 6] = s;
    __syncthreads();
    if (threadIdx.x == 0)
        out[0] = (red[0] + red[1] + red[2] + red[3]) *
                 (1.0f / (8191.0f * 8192.0f));
}

extern "C" void kernel_launch(void* const* d_in, const int* in_sizes, int n_in,
                              void* d_out, int out_size, void* d_ws, size_t ws_size,
                              hipStream_t stream) {
    const float* x = (const float*)d_in[0];
    float* out = (float*)d_out;
    unsigned char* xq = (unsigned char*)d_ws;                // 8 MB fp4 matrix
    float* partials = (float*)((char*)d_ws + (size_t)N_CLS * DIMB);

    normalize_rows<<<N_CLS / 4, 256, 0, stream>>>(x, xq);
    gram_tile<<<NTILES, 256, 0, stream>>>((const char*)xq, partials);
    finalize<<<1, 256, 0, stream>>>(partials, out);
}